// Round 7
// baseline (407.750 us; speedup 1.0000x reference)
//
#include <hip/hip_runtime.h>
#include <hip/hip_fp16.h>
#include <math.h>

#define GB 64        // graphs in batch
#define AD 8         // n_actions
#define NC2 1024     // edge chunks for hist/fill
#define BSH 6        // bucket shift -> bucket covers 64 consecutive dst nodes
#define BS  64       // bucket size (nodes)
#define NBMAX 1024   // max coarse buckets (n <= 65536; src packing needs n <= 65536)

// ---- pass 1: per-chunk LDS histogram of coarse bucket (dst>>6) ----
__global__ __launch_bounds__(256) void k_hist2(const int* __restrict__ ei,
                                               int* __restrict__ H2,
                                               int E, int ce, int NB) {
    __shared__ int h[NBMAX];
    int c = blockIdx.x;
    for (int b = threadIdx.x; b < NB; b += 256) h[b] = 0;
    __syncthreads();
    int e0 = c * ce, e1 = min(e0 + ce, E);
    for (int e = e0 + threadIdx.x; e < e1; e += 256)
        atomicAdd(&h[ei[E + e] >> BSH], 1);            // LDS atomic
    __syncthreads();
    for (int b = threadIdx.x; b < NB; b += 256)
        H2[(size_t)c * NB + b] = h[b];                 // coalesced
}

// ---- pass 2: per-bucket exclusive prefix across chunks (one block per bucket) ----
__global__ __launch_bounds__(256) void k_cscan(int* __restrict__ H2,
                                               int* __restrict__ cntB,
                                               int NB, int nc) {
    __shared__ int ssum[256];
    int b = blockIdx.x;                    // bucket
    int t = threadIdx.x;
    int v[4];
    int local = 0;
    #pragma unroll
    for (int k = 0; k < 4; k++) {
        int c = t * 4 + k;                 // nc == 1024 == 256*4
        v[k] = (c < nc) ? H2[(size_t)c * NB + b] : 0;
        local += v[k];
    }
    ssum[t] = local;
    __syncthreads();
    for (int s = 1; s < 256; s <<= 1) {
        int tmp = (t >= s) ? ssum[t - s] : 0;
        __syncthreads();
        ssum[t] += tmp;
        __syncthreads();
    }
    int run = ssum[t] - local;
    #pragma unroll
    for (int k = 0; k < 4; k++) {
        int c = t * 4 + k;
        if (c < nc) H2[(size_t)c * NB + b] = run;
        run += v[k];
    }
    if (t == 255) cntB[b] = ssum[255];
}

// ---- pass 3: exclusive scan of bucket totals -> bb[]; sentinels ----
__global__ __launch_bounds__(1024) void k_bscan(const int* __restrict__ cntB,
                                                int* __restrict__ bb,
                                                int* __restrict__ rowptr,
                                                int NB, int n, int E) {
    __shared__ int sm[1024];
    int t = threadIdx.x;
    int v = (t < NB) ? cntB[t] : 0;
    sm[t] = v;
    __syncthreads();
    for (int s = 1; s < 1024; s <<= 1) {
        int tmp = (t >= s) ? sm[t - s] : 0;
        __syncthreads();
        sm[t] += tmp;
        __syncthreads();
    }
    if (t < NB) bb[t] = sm[t] - v;                     // exclusive
    if (t == NB - 1) bb[NB] = sm[t];                   // == E
    if (t == 0) rowptr[n] = E;                         // CSR sentinel
}

// ---- pass 4: edge MLP + scatter records into coarse buckets ----
__global__ __launch_bounds__(256) void k_fill2(const int* __restrict__ ei,
                                               const float* __restrict__ attr,
                                               const float* __restrict__ W_e1,
                                               const float* __restrict__ b_e1,
                                               const float* __restrict__ W_e2,
                                               const float* __restrict__ b_e2,
                                               const int* __restrict__ bb,
                                               const int* __restrict__ H2,
                                               int2* __restrict__ rec,
                                               int E, int ce, int NB) {
    __shared__ int off[NBMAX];
    int c = blockIdx.x;
    for (int b = threadIdx.x; b < NB; b += 256)
        off[b] = bb[b] + H2[(size_t)c * NB + b];
    __syncthreads();
    float w1s = W_e1[0], w1d = W_e1[1], w1a = W_e1[2], bb1 = b_e1[0];
    float w2 = W_e2[0], bb2 = b_e2[0];
    int e0 = c * ce, e1 = min(e0 + ce, E);
    for (int e = e0 + threadIdx.x; e < e1; e += 256) {
        int d = ei[E + e];
        int s = ei[e];
        float h = fmaxf((float)s * w1s + (float)d * w1d + attr[e] * w1a + bb1, 0.0f);
        float w = 1.0f / (1.0f + expf(-(h * w2 + bb2)));
        int pos = atomicAdd(&off[d >> BSH], 1);        // LDS atomic
        int2 rv;
        rv.x = s | ((d & (BS - 1)) << 16);
        rv.y = __float_as_int(w);
        rec[pos] = rv;
    }
}

// ---- pass 5: per-bucket node sort + degree + dis + rowptr ----
__global__ __launch_bounds__(256) void k_bucket(const int2* __restrict__ rec,
                                                const int* __restrict__ bb,
                                                int2* __restrict__ rec2,
                                                int* __restrict__ rowptr,
                                                float* __restrict__ dis, int n) {
    __shared__ int   cntL[BS];
    __shared__ float degL[BS];
    __shared__ int   pfx[BS];
    __shared__ int   cnt2[BS];
    int b = blockIdx.x;
    int t = threadIdx.x;
    if (t < BS) { cntL[t] = 0; degL[t] = 1.0f; cnt2[t] = 0; }   // self-loop deg=1
    __syncthreads();
    int s0 = bb[b], s1 = bb[b + 1];
    for (int j = s0 + t; j < s1; j += 256) {
        int2 rv = rec[j];
        int dl = (rv.x >> 16) & (BS - 1);
        atomicAdd(&cntL[dl], 1);
        atomicAdd(&degL[dl], __int_as_float(rv.y));    // LDS fp32 atomic
    }
    __syncthreads();
    if (t == 0) {
        int acc = 0;
        for (int k = 0; k < BS; k++) { pfx[k] = acc; acc += cntL[k]; }
    }
    __syncthreads();
    int lo = b << BSH;
    if (t < BS) {
        int i = lo + t;
        if (i < n) {
            rowptr[i] = s0 + pfx[t];
            dis[i] = rsqrtf(degL[t]);
        }
    }
    for (int j = s0 + t; j < s1; j += 256) {
        int2 rv = rec[j];
        int dl = (rv.x >> 16) & (BS - 1);
        int r = atomicAdd(&cnt2[dl], 1);
        int2 o;
        o.x = rv.x & 0xFFFF;
        o.y = rv.y;
        rec2[s0 + pfx[dl] + r] = o;
    }
}

// ---- pass 6: fold dis[src] into record weight, pack to 4 B ----
// rec3[j] = src | fp16(w * dis[src]) << 16
__global__ __launch_bounds__(256) void k_fold(const int2* __restrict__ rec2,
                                              const float* __restrict__ dis,
                                              unsigned int* __restrict__ rec3, int E) {
    int j = blockIdx.x * 256 + threadIdx.x;
    if (j >= E) return;
    int2 rv = rec2[j];
    int s = rv.x & 0xFFFF;
    float w = __int_as_float(rv.y) * dis[s];
    unsigned int h = (unsigned int)__half_as_ushort(__float2half(w));
    rec3[j] = (unsigned int)s | (h << 16);
}

// ---- xw = x @ W_gcn, stored fp16 PLANAR: xwp[p][n][32], p = feature/32 ----
__global__ __launch_bounds__(256) void k_xw(const float* __restrict__ x,
                                            const float* __restrict__ Wg,
                                            __half* __restrict__ xwp, int n) {
    __shared__ float xs[16 * 128];
    int block_row = blockIdx.x * 16;
    int tid = threadIdx.x;
    #pragma unroll
    for (int i = 0; i < 8; i++) {
        int idx = tid + i * 256;
        int r = idx >> 7, c = idx & 127;
        int gr = block_row + r;
        xs[idx] = (gr < n) ? x[(size_t)gr * 128 + c] : 0.0f;
    }
    __syncthreads();
    int c = tid & 127;
    int rbase = (tid >> 7) * 8;
    float acc[8] = {0, 0, 0, 0, 0, 0, 0, 0};
    for (int k = 0; k < 128; k++) {
        float wv = Wg[k * 128 + c];
        #pragma unroll
        for (int r = 0; r < 8; r++)
            acc[r] += xs[(rbase + r) * 128 + k] * wv;
    }
    size_t plane_off = (size_t)(c >> 5) * (size_t)n * 32 + (c & 31);
    #pragma unroll
    for (int r = 0; r < 8; r++) {
        int gr = block_row + rbase + r;
        if (gr < n) xwp[plane_off + (size_t)gr * 32] = __float2half(acc[r]);
    }
}

// ---- gather, feature-split: pass p covers features [32p, 32p+32) ----
// wave per node; lanes 0-31 even edges, 32-63 odd edges; feature = lane&31
__global__ __launch_bounds__(256) void k_gather(const unsigned int* __restrict__ rec3,
                                                const int* __restrict__ rowptr,
                                                const float* __restrict__ dis,
                                                const __half* __restrict__ xwp,
                                                const float* __restrict__ bg,
                                                float* __restrict__ conv, int n) {
    int wave = threadIdx.x >> 6;
    int lane = threadIdx.x & 63;
    int p = blockIdx.y;
    int i = blockIdx.x * 4 + wave;
    if (i >= n) return;                      // wave-uniform
    const __half* plane = xwp + (size_t)p * (size_t)n * 32;
    int fl = lane & 31;
    int hid = lane >> 5;
    int st = rowptr[i];
    int m = rowptr[i + 1] - st;
    float di = dis[i];
    float acc = (hid == 0) ? di * __half2float(plane[(size_t)i * 32 + fl]) : 0.0f;
    for (int base = 0; base < m; base += 64) {
        int k = min(64, m - base);
        unsigned int rv = 0u;
        if (lane < k) rv = rec3[st + base + lane];
        int pairs = (k + 1) >> 1;
        for (int j = 0; j < pairs; j++) {
            int eslot = 2 * j + hid;        // per-lane index -> ds_bpermute
            unsigned int rvj = (unsigned int)__builtin_amdgcn_ds_bpermute(eslot << 2, (int)rv);
            int s = rvj & 0xFFFF;
            float cf = __half2float(__ushort_as_half((unsigned short)(rvj >> 16)));
            // eslot >= k pulls from a lane that stayed 0 -> cf = 0, s = 0 (harmless)
            acc += cf * __half2float(plane[(size_t)s * 32 + fl]);
        }
    }
    acc += __shfl_xor(acc, 32);              // combine even/odd halves
    if (hid == 0) {
        float o = di * acc + bg[p * 32 + fl];
        conv[(size_t)i * 128 + p * 32 + fl] = fmaxf(o, 0.0f);
    }
}

// ---- mean-pool: batch sorted -> running accumulate, flush on change ----
__global__ __launch_bounds__(128) void k_pool(const float* __restrict__ h1,
                                              const int* __restrict__ batch,
                                              float* __restrict__ psum,
                                              float* __restrict__ pcnt, int n) {
    int f = threadIdx.x;
    int n0 = blockIdx.x * 64;
    if (n0 >= n) return;
    int n1 = min(n0 + 64, n);
    int cur = batch[n0];
    float acc = 0.0f, cnt = 0.0f;
    for (int i = n0; i < n1; i++) {
        int g = batch[i];
        if (g != cur) {
            atomicAdd(&psum[cur * 128 + f], acc);
            if (f == 0) atomicAdd(&pcnt[cur], cnt);
            acc = 0.0f; cnt = 0.0f; cur = g;
        }
        acc += h1[(size_t)i * 128 + f];
        cnt += 1.0f;
    }
    atomicAdd(&psum[cur * 128 + f], acc);
    if (f == 0) atomicAdd(&pcnt[cur], cnt);
}

// ---- head: pooled = psum/cnt; h2 = relu(pooled@W2+b2); out = h2@W3+b3 ----
__global__ __launch_bounds__(128) void k_head(const float* __restrict__ psum,
                                              const float* __restrict__ pcnt,
                                              const float* __restrict__ W2,
                                              const float* __restrict__ b2,
                                              const float* __restrict__ W3,
                                              const float* __restrict__ b3,
                                              float* __restrict__ out) {
    __shared__ float pl[128];
    __shared__ float h2s[128];
    int g = blockIdx.x;
    int t = threadIdx.x;
    float c = fmaxf(pcnt[g], 1.0f);
    pl[t] = psum[g * 128 + t] / c;
    __syncthreads();
    float acc = b2[t];
    for (int k = 0; k < 128; k++) acc += pl[k] * W2[k * 128 + t];
    h2s[t] = fmaxf(acc, 0.0f);
    __syncthreads();
    if (t < AD) {
        float o = b3[t];
        for (int k = 0; k < 128; k++) o += h2s[k] * W3[k * AD + t];
        out[g * AD + t] = o;
    }
}

extern "C" void kernel_launch(void* const* d_in, const int* in_sizes, int n_in,
                              void* d_out, int out_size, void* d_ws, size_t ws_size,
                              hipStream_t stream) {
    const float* x        = (const float*)d_in[0];
    const float* edge_attr= (const float*)d_in[1];
    const float* W_e1     = (const float*)d_in[2];
    const float* b_e1     = (const float*)d_in[3];
    const float* W_e2     = (const float*)d_in[4];
    const float* b_e2     = (const float*)d_in[5];
    const float* W_gcn    = (const float*)d_in[6];
    const float* b_gcn    = (const float*)d_in[7];
    const float* W2       = (const float*)d_in[8];
    const float* b2       = (const float*)d_in[9];
    const float* W3       = (const float*)d_in[10];
    const float* b3       = (const float*)d_in[11];
    const int*   ei       = (const int*)d_in[12];
    const int*   batch    = (const int*)d_in[13];
    float* out = (float*)d_out;

    const int E  = in_sizes[12] / 2;          // 1,600,000
    const int n  = in_sizes[13];              // 50,000 (<= 65536 for packing)
    const int NB = (n + BS - 1) >> BSH;       // 782 coarse buckets
    const int ce = (E + NC2 - 1) / NC2;       // 1563 edges per chunk

    // workspace layout (~64.4 MB; conv hosts H2; rec hosts rec3)
    char* p = (char*)d_ws;
    __half* xwp   = (__half*)p;  p += (size_t)n * 128 * sizeof(__half);   // 12.8 MB planar
    int*    H2    = (int*)p;                                              // 3.2 MB, aliases conv
    float*  conv  = (float*)p;   p += (size_t)n * 128 * sizeof(float);    // 25.6 MB
    int2*   rec   = (int2*)p;    p += (size_t)E * sizeof(int2);           // 12.8 MB
    unsigned int* rec3 = (unsigned int*)rec;                              // aliases rec (dead after k_bucket)
    int2*   rec2  = (int2*)p;    p += (size_t)E * sizeof(int2);           // 12.8 MB
    float*  dis   = (float*)p;   p += (size_t)n * sizeof(float);
    float*  psum  = (float*)p;   p += (size_t)GB * 128 * sizeof(float);
    float*  pcnt  = (float*)p;   p += (size_t)GB * sizeof(float);
    int*    rowptr= (int*)p;     p += (size_t)(n + 1) * sizeof(int);
    int*    cntB  = (int*)p;     p += (size_t)NBMAX * sizeof(int);
    int*    bb    = (int*)p;     p += (size_t)(NBMAX + 1) * sizeof(int);

    hipMemsetAsync(psum, 0, (GB * 128 + GB) * sizeof(float), stream);

    k_xw<<<(n + 15) / 16, 256, 0, stream>>>(x, W_gcn, xwp, n);
    k_hist2<<<NC2, 256, 0, stream>>>(ei, H2, E, ce, NB);
    k_cscan<<<NB, 256, 0, stream>>>(H2, cntB, NB, NC2);
    k_bscan<<<1, 1024, 0, stream>>>(cntB, bb, rowptr, NB, n, E);
    k_fill2<<<NC2, 256, 0, stream>>>(ei, edge_attr, W_e1, b_e1, W_e2, b_e2,
                                     bb, H2, rec, E, ce, NB);
    k_bucket<<<NB, 256, 0, stream>>>(rec, bb, rec2, rowptr, dis, n);
    k_fold<<<(E + 255) / 256, 256, 0, stream>>>(rec2, dis, rec3, E);
    k_gather<<<dim3((n + 3) / 4, 4), 256, 0, stream>>>(rec3, rowptr, dis, xwp,
                                                       b_gcn, conv, n);
    k_pool<<<(n + 63) / 64, 128, 0, stream>>>(conv, batch, psum, pcnt, n);
    k_head<<<GB, 128, 0, stream>>>(psum, pcnt, W2, b2, W3, b3, out);
}

// Round 8
// 296.896 us; speedup vs baseline: 1.3734x; 1.3734x over previous
//
#include <hip/hip_runtime.h>
#include <hip/hip_fp16.h>
#include <math.h>

#define GB 64        // graphs in batch
#define AD 8         // n_actions
#define NC2 1024     // edge chunks for hist/fill
#define BSH 6        // bucket shift -> bucket covers 64 consecutive dst nodes
#define BS  64       // bucket size (nodes)
#define NBMAX 1024   // max coarse buckets (n <= 65536; src packing needs n <= 65536)

// ---- pass 1: per-chunk LDS histogram of coarse bucket (dst>>6) ----
__global__ __launch_bounds__(256) void k_hist2(const int* __restrict__ ei,
                                               int* __restrict__ H2,
                                               int E, int ce, int NB) {
    __shared__ int h[NBMAX];
    int c = blockIdx.x;
    for (int b = threadIdx.x; b < NB; b += 256) h[b] = 0;
    __syncthreads();
    int e0 = c * ce, e1 = min(e0 + ce, E);
    for (int e = e0 + threadIdx.x; e < e1; e += 256)
        atomicAdd(&h[ei[E + e] >> BSH], 1);            // LDS atomic
    __syncthreads();
    for (int b = threadIdx.x; b < NB; b += 256)
        H2[(size_t)c * NB + b] = h[b];                 // coalesced
}

// ---- pass 2: per-bucket exclusive prefix across chunks (one block per bucket) ----
__global__ __launch_bounds__(256) void k_cscan(int* __restrict__ H2,
                                               int* __restrict__ cntB,
                                               int NB, int nc) {
    __shared__ int ssum[256];
    int b = blockIdx.x;                    // bucket
    int t = threadIdx.x;
    int v[4];
    int local = 0;
    #pragma unroll
    for (int k = 0; k < 4; k++) {
        int c = t * 4 + k;                 // nc == 1024 == 256*4
        v[k] = (c < nc) ? H2[(size_t)c * NB + b] : 0;
        local += v[k];
    }
    ssum[t] = local;
    __syncthreads();
    for (int s = 1; s < 256; s <<= 1) {
        int tmp = (t >= s) ? ssum[t - s] : 0;
        __syncthreads();
        ssum[t] += tmp;
        __syncthreads();
    }
    int run = ssum[t] - local;
    #pragma unroll
    for (int k = 0; k < 4; k++) {
        int c = t * 4 + k;
        if (c < nc) H2[(size_t)c * NB + b] = run;
        run += v[k];
    }
    if (t == 255) cntB[b] = ssum[255];
}

// ---- pass 3: exclusive scan of bucket totals -> bb[]; sentinels ----
__global__ __launch_bounds__(1024) void k_bscan(const int* __restrict__ cntB,
                                                int* __restrict__ bb,
                                                int* __restrict__ rowptr,
                                                int NB, int n, int E) {
    __shared__ int sm[1024];
    int t = threadIdx.x;
    int v = (t < NB) ? cntB[t] : 0;
    sm[t] = v;
    __syncthreads();
    for (int s = 1; s < 1024; s <<= 1) {
        int tmp = (t >= s) ? sm[t - s] : 0;
        __syncthreads();
        sm[t] += tmp;
        __syncthreads();
    }
    if (t < NB) bb[t] = sm[t] - v;                     // exclusive
    if (t == NB - 1) bb[NB] = sm[t];                   // == E
    if (t == 0) rowptr[n] = E;                         // CSR sentinel
}

// ---- pass 4: edge MLP + scatter records into coarse buckets ----
__global__ __launch_bounds__(256) void k_fill2(const int* __restrict__ ei,
                                               const float* __restrict__ attr,
                                               const float* __restrict__ W_e1,
                                               const float* __restrict__ b_e1,
                                               const float* __restrict__ W_e2,
                                               const float* __restrict__ b_e2,
                                               const int* __restrict__ bb,
                                               const int* __restrict__ H2,
                                               int2* __restrict__ rec,
                                               int E, int ce, int NB) {
    __shared__ int off[NBMAX];
    int c = blockIdx.x;
    for (int b = threadIdx.x; b < NB; b += 256)
        off[b] = bb[b] + H2[(size_t)c * NB + b];
    __syncthreads();
    float w1s = W_e1[0], w1d = W_e1[1], w1a = W_e1[2], bb1 = b_e1[0];
    float w2 = W_e2[0], bb2 = b_e2[0];
    int e0 = c * ce, e1 = min(e0 + ce, E);
    for (int e = e0 + threadIdx.x; e < e1; e += 256) {
        int d = ei[E + e];
        int s = ei[e];
        float h = fmaxf((float)s * w1s + (float)d * w1d + attr[e] * w1a + bb1, 0.0f);
        float w = 1.0f / (1.0f + expf(-(h * w2 + bb2)));
        int pos = atomicAdd(&off[d >> BSH], 1);        // LDS atomic
        int2 rv;
        rv.x = s | ((d & (BS - 1)) << 16);
        rv.y = __float_as_int(w);
        rec[pos] = rv;
    }
}

// ---- pass 5: per-bucket node sort + degree + dis + rowptr ----
__global__ __launch_bounds__(256) void k_bucket(const int2* __restrict__ rec,
                                                const int* __restrict__ bb,
                                                int2* __restrict__ rec2,
                                                int* __restrict__ rowptr,
                                                float* __restrict__ dis, int n) {
    __shared__ int   cntL[BS];
    __shared__ float degL[BS];
    __shared__ int   pfx[BS];
    __shared__ int   cnt2[BS];
    int b = blockIdx.x;
    int t = threadIdx.x;
    if (t < BS) { cntL[t] = 0; degL[t] = 1.0f; cnt2[t] = 0; }   // self-loop deg=1
    __syncthreads();
    int s0 = bb[b], s1 = bb[b + 1];
    for (int j = s0 + t; j < s1; j += 256) {
        int2 rv = rec[j];
        int dl = (rv.x >> 16) & (BS - 1);
        atomicAdd(&cntL[dl], 1);
        atomicAdd(&degL[dl], __int_as_float(rv.y));    // LDS fp32 atomic
    }
    __syncthreads();
    if (t == 0) {
        int acc = 0;
        for (int k = 0; k < BS; k++) { pfx[k] = acc; acc += cntL[k]; }
    }
    __syncthreads();
    int lo = b << BSH;
    if (t < BS) {
        int i = lo + t;
        if (i < n) {
            rowptr[i] = s0 + pfx[t];
            dis[i] = rsqrtf(degL[t]);
        }
    }
    for (int j = s0 + t; j < s1; j += 256) {
        int2 rv = rec[j];
        int dl = (rv.x >> 16) & (BS - 1);
        int r = atomicAdd(&cnt2[dl], 1);
        int2 o;
        o.x = rv.x & 0xFFFF;
        o.y = rv.y;
        rec2[s0 + pfx[dl] + r] = o;
    }
}

// ---- pass 6: fold dis[src] into record weight, pack to 4 B ----
// rec3[j] = src | fp16(w * dis[src]) << 16
__global__ __launch_bounds__(256) void k_fold(const int2* __restrict__ rec2,
                                              const float* __restrict__ dis,
                                              unsigned int* __restrict__ rec3, int E) {
    int j = blockIdx.x * 256 + threadIdx.x;
    if (j >= E) return;
    int2 rv = rec2[j];
    int s = rv.x & 0xFFFF;
    float w = __int_as_float(rv.y) * dis[s];
    unsigned int h = (unsigned int)__half_as_ushort(__float2half(w));
    rec3[j] = (unsigned int)s | (h << 16);
}

// ---- xw = x @ W_gcn, stored fp16 row-major (M=50000, K=128, N=128) ----
__global__ __launch_bounds__(256) void k_xw(const float* __restrict__ x,
                                            const float* __restrict__ Wg,
                                            __half* __restrict__ xwh, int n) {
    __shared__ float xs[16 * 128];
    int block_row = blockIdx.x * 16;
    int tid = threadIdx.x;
    #pragma unroll
    for (int i = 0; i < 8; i++) {
        int idx = tid + i * 256;
        int r = idx >> 7, c = idx & 127;
        int gr = block_row + r;
        xs[idx] = (gr < n) ? x[(size_t)gr * 128 + c] : 0.0f;
    }
    __syncthreads();
    int c = tid & 127;
    int rbase = (tid >> 7) * 8;
    float acc[8] = {0, 0, 0, 0, 0, 0, 0, 0};
    for (int k = 0; k < 128; k++) {
        float wv = Wg[k * 128 + c];
        #pragma unroll
        for (int r = 0; r < 8; r++)
            acc[r] += xs[(rbase + r) * 128 + k] * wv;
    }
    #pragma unroll
    for (int r = 0; r < 8; r++) {
        int gr = block_row + rbase + r;
        if (gr < n) xwh[(size_t)gr * 128 + c] = __float2half(acc[r]);
    }
}

// ---- gather: wave per node; 4 groups x 16 lanes; group g takes edge 4j+g,
// lane q loads 16 B (8 fp16 feats) of the src row -> 1 KB per load instr ----
__global__ __launch_bounds__(256) void k_gather(const unsigned int* __restrict__ rec3,
                                                const int* __restrict__ rowptr,
                                                const float* __restrict__ dis,
                                                const __half* __restrict__ xh,
                                                const float* __restrict__ bg,
                                                float* __restrict__ conv, int n) {
    int wave = threadIdx.x >> 6;
    int lane = threadIdx.x & 63;
    int g = lane >> 4;          // edge group 0..3
    int q = lane & 15;          // lane in group; features q*8 .. q*8+7
    int i = blockIdx.x * 4 + wave;
    if (i >= n) return;                      // wave-uniform
    int st = rowptr[i];
    int m = rowptr[i + 1] - st;
    float di = dis[i];
    float acc[8];
    {
        uint4 sr = *(const uint4*)(xh + (size_t)i * 128 + q * 8);
        const __half2* hp = (const __half2*)&sr;
        float sc = (g == 0) ? di : 0.0f;     // self term counted once
        #pragma unroll
        for (int k = 0; k < 4; k++) {
            float2 f = __half22float2(hp[k]);
            acc[2 * k]     = sc * f.x;
            acc[2 * k + 1] = sc * f.y;
        }
    }
    for (int base = 0; base < m; base += 64) {
        int kk = min(64, m - base);
        unsigned int rv = 0u;
        if (lane < kk) rv = rec3[st + base + lane];
        int jn = (kk + 3) >> 2;
        #pragma unroll 4
        for (int j = 0; j < jn; j++) {
            // group g pulls record slot 4j+g; slots >= kk pull staged 0 -> cf=0
            unsigned int rvj = (unsigned int)__builtin_amdgcn_ds_bpermute(
                                   ((j << 2) + g) << 2, (int)rv);
            int s = rvj & 0xFFFF;
            float cf = __half2float(__ushort_as_half((unsigned short)(rvj >> 16)));
            uint4 rw = *(const uint4*)(xh + (size_t)s * 128 + q * 8);
            const __half2* rp = (const __half2*)&rw;
            #pragma unroll
            for (int k = 0; k < 4; k++) {
                float2 f = __half22float2(rp[k]);
                acc[2 * k]     += cf * f.x;
                acc[2 * k + 1] += cf * f.y;
            }
        }
    }
    #pragma unroll
    for (int k = 0; k < 8; k++) {            // butterfly: merge 4 group partials
        acc[k] += __shfl_xor(acc[k], 16);
        acc[k] += __shfl_xor(acc[k], 32);
    }
    if (g < 2) {                             // 32 lanes write the 512 B row
        int c0 = q * 8 + g * 4;
        float4 bgv = *(const float4*)(bg + c0);
        int kb = g * 4;
        float4 o;
        o.x = fmaxf(di * acc[kb + 0] + bgv.x, 0.0f);
        o.y = fmaxf(di * acc[kb + 1] + bgv.y, 0.0f);
        o.z = fmaxf(di * acc[kb + 2] + bgv.z, 0.0f);
        o.w = fmaxf(di * acc[kb + 3] + bgv.w, 0.0f);
        *(float4*)(conv + (size_t)i * 128 + c0) = o;
    }
}

// ---- mean-pool: batch sorted -> running accumulate, flush on change ----
__global__ __launch_bounds__(128) void k_pool(const float* __restrict__ h1,
                                              const int* __restrict__ batch,
                                              float* __restrict__ psum,
                                              float* __restrict__ pcnt, int n) {
    int f = threadIdx.x;
    int n0 = blockIdx.x * 64;
    if (n0 >= n) return;
    int n1 = min(n0 + 64, n);
    int cur = batch[n0];
    float acc = 0.0f, cnt = 0.0f;
    for (int i = n0; i < n1; i++) {
        int g = batch[i];
        if (g != cur) {
            atomicAdd(&psum[cur * 128 + f], acc);
            if (f == 0) atomicAdd(&pcnt[cur], cnt);
            acc = 0.0f; cnt = 0.0f; cur = g;
        }
        acc += h1[(size_t)i * 128 + f];
        cnt += 1.0f;
    }
    atomicAdd(&psum[cur * 128 + f], acc);
    if (f == 0) atomicAdd(&pcnt[cur], cnt);
}

// ---- head: pooled = psum/cnt; h2 = relu(pooled@W2+b2); out = h2@W3+b3 ----
__global__ __launch_bounds__(128) void k_head(const float* __restrict__ psum,
                                              const float* __restrict__ pcnt,
                                              const float* __restrict__ W2,
                                              const float* __restrict__ b2,
                                              const float* __restrict__ W3,
                                              const float* __restrict__ b3,
                                              float* __restrict__ out) {
    __shared__ float pl[128];
    __shared__ float h2s[128];
    int g = blockIdx.x;
    int t = threadIdx.x;
    float c = fmaxf(pcnt[g], 1.0f);
    pl[t] = psum[g * 128 + t] / c;
    __syncthreads();
    float acc = b2[t];
    for (int k = 0; k < 128; k++) acc += pl[k] * W2[k * 128 + t];
    h2s[t] = fmaxf(acc, 0.0f);
    __syncthreads();
    if (t < AD) {
        float o = b3[t];
        for (int k = 0; k < 128; k++) o += h2s[k] * W3[k * AD + t];
        out[g * AD + t] = o;
    }
}

extern "C" void kernel_launch(void* const* d_in, const int* in_sizes, int n_in,
                              void* d_out, int out_size, void* d_ws, size_t ws_size,
                              hipStream_t stream) {
    const float* x        = (const float*)d_in[0];
    const float* edge_attr= (const float*)d_in[1];
    const float* W_e1     = (const float*)d_in[2];
    const float* b_e1     = (const float*)d_in[3];
    const float* W_e2     = (const float*)d_in[4];
    const float* b_e2     = (const float*)d_in[5];
    const float* W_gcn    = (const float*)d_in[6];
    const float* b_gcn    = (const float*)d_in[7];
    const float* W2       = (const float*)d_in[8];
    const float* b2       = (const float*)d_in[9];
    const float* W3       = (const float*)d_in[10];
    const float* b3       = (const float*)d_in[11];
    const int*   ei       = (const int*)d_in[12];
    const int*   batch    = (const int*)d_in[13];
    float* out = (float*)d_out;

    const int E  = in_sizes[12] / 2;          // 1,600,000
    const int n  = in_sizes[13];              // 50,000 (<= 65536 for packing)
    const int NB = (n + BS - 1) >> BSH;       // 782 coarse buckets
    const int ce = (E + NC2 - 1) / NC2;       // 1563 edges per chunk

    // workspace layout (~64.4 MB; conv hosts H2; rec hosts rec3)
    char* p = (char*)d_ws;
    __half* xwh   = (__half*)p;  p += (size_t)n * 128 * sizeof(__half);   // 12.8 MB
    int*    H2    = (int*)p;                                              // 3.2 MB, aliases conv
    float*  conv  = (float*)p;   p += (size_t)n * 128 * sizeof(float);    // 25.6 MB
    int2*   rec   = (int2*)p;    p += (size_t)E * sizeof(int2);           // 12.8 MB
    unsigned int* rec3 = (unsigned int*)rec;                              // aliases rec (dead after k_bucket)
    int2*   rec2  = (int2*)p;    p += (size_t)E * sizeof(int2);           // 12.8 MB
    float*  dis   = (float*)p;   p += (size_t)n * sizeof(float);
    float*  psum  = (float*)p;   p += (size_t)GB * 128 * sizeof(float);
    float*  pcnt  = (float*)p;   p += (size_t)GB * sizeof(float);
    int*    rowptr= (int*)p;     p += (size_t)(n + 1) * sizeof(int);
    int*    cntB  = (int*)p;     p += (size_t)NBMAX * sizeof(int);
    int*    bb    = (int*)p;     p += (size_t)(NBMAX + 1) * sizeof(int);

    hipMemsetAsync(psum, 0, (GB * 128 + GB) * sizeof(float), stream);

    k_xw<<<(n + 15) / 16, 256, 0, stream>>>(x, W_gcn, xwh, n);
    k_hist2<<<NC2, 256, 0, stream>>>(ei, H2, E, ce, NB);
    k_cscan<<<NB, 256, 0, stream>>>(H2, cntB, NB, NC2);
    k_bscan<<<1, 1024, 0, stream>>>(cntB, bb, rowptr, NB, n, E);
    k_fill2<<<NC2, 256, 0, stream>>>(ei, edge_attr, W_e1, b_e1, W_e2, b_e2,
                                     bb, H2, rec, E, ce, NB);
    k_bucket<<<NB, 256, 0, stream>>>(rec, bb, rec2, rowptr, dis, n);
    k_fold<<<(E + 255) / 256, 256, 0, stream>>>(rec2, dis, rec3, E);
    k_gather<<<(n + 3) / 4, 256, 0, stream>>>(rec3, rowptr, dis, xwh,
                                              b_gcn, conv, n);
    k_pool<<<(n + 63) / 64, 128, 0, stream>>>(conv, batch, psum, pcnt, n);
    k_head<<<GB, 128, 0, stream>>>(psum, pcnt, W2, b2, W3, b3, out);
}

// Round 9
// 283.347 us; speedup vs baseline: 1.4390x; 1.0478x over previous
//
#include <hip/hip_runtime.h>
#include <hip/hip_fp16.h>
#include <math.h>

#define GB 64        // graphs in batch
#define AD 8         // n_actions
#define NC2 1024     // edge chunks for hist/fill
#define BSH 6        // bucket shift -> bucket covers 64 consecutive dst nodes
#define BS  64       // bucket size (nodes)
#define NBMAX 1024   // max coarse buckets (n <= 65536; src packing needs n <= 65536)

// ---- pass 1: per-chunk LDS histogram of coarse bucket (dst>>6) ----
__global__ __launch_bounds__(256) void k_hist2(const int* __restrict__ ei,
                                               int* __restrict__ H2,
                                               int E, int ce, int NB) {
    __shared__ int h[NBMAX];
    int c = blockIdx.x;
    for (int b = threadIdx.x; b < NB; b += 256) h[b] = 0;
    __syncthreads();
    int e0 = c * ce, e1 = min(e0 + ce, E);
    int nv = (e1 - e0) & ~3;
    const int4* dst4 = (const int4*)(ei + E + e0);
    for (int v = threadIdx.x; v < (nv >> 2); v += 256) {
        int4 d = dst4[v];
        atomicAdd(&h[d.x >> BSH], 1);
        atomicAdd(&h[d.y >> BSH], 1);
        atomicAdd(&h[d.z >> BSH], 1);
        atomicAdd(&h[d.w >> BSH], 1);
    }
    for (int e = e0 + nv + threadIdx.x; e < e1; e += 256)   // tail
        atomicAdd(&h[ei[E + e] >> BSH], 1);
    __syncthreads();
    for (int b = threadIdx.x; b < NB; b += 256)
        H2[(size_t)c * NB + b] = h[b];                 // coalesced
}

// ---- pass 2: per-bucket exclusive prefix across chunks (one block per bucket) ----
__global__ __launch_bounds__(256) void k_cscan(int* __restrict__ H2,
                                               int* __restrict__ cntB,
                                               int NB, int nc) {
    __shared__ int ssum[256];
    int b = blockIdx.x;
    int t = threadIdx.x;
    int v[4];
    int local = 0;
    #pragma unroll
    for (int k = 0; k < 4; k++) {
        int c = t * 4 + k;                 // nc == 1024 == 256*4
        v[k] = (c < nc) ? H2[(size_t)c * NB + b] : 0;
        local += v[k];
    }
    ssum[t] = local;
    __syncthreads();
    for (int s = 1; s < 256; s <<= 1) {
        int tmp = (t >= s) ? ssum[t - s] : 0;
        __syncthreads();
        ssum[t] += tmp;
        __syncthreads();
    }
    int run = ssum[t] - local;
    #pragma unroll
    for (int k = 0; k < 4; k++) {
        int c = t * 4 + k;
        if (c < nc) H2[(size_t)c * NB + b] = run;
        run += v[k];
    }
    if (t == 255) cntB[b] = ssum[255];
}

// ---- pass 3: scan bucket totals -> bb[]; sentinels; zero psum/pcnt ----
__global__ __launch_bounds__(1024) void k_bscan(const int* __restrict__ cntB,
                                                int* __restrict__ bb,
                                                int* __restrict__ rowptr,
                                                float* __restrict__ psum,
                                                int NB, int n, int E) {
    __shared__ int sm[1024];
    int t = threadIdx.x;
    for (int z = t; z < GB * 128 + GB; z += 1024) psum[z] = 0.0f;  // psum+pcnt
    int v = (t < NB) ? cntB[t] : 0;
    sm[t] = v;
    __syncthreads();
    for (int s = 1; s < 1024; s <<= 1) {
        int tmp = (t >= s) ? sm[t - s] : 0;
        __syncthreads();
        sm[t] += tmp;
        __syncthreads();
    }
    if (t < NB) bb[t] = sm[t] - v;                     // exclusive
    if (t == NB - 1) bb[NB] = sm[t];                   // == E
    if (t == 0) rowptr[n] = E;                         // CSR sentinel
}

// ---- pass 4: edge MLP + scatter 8 B records into coarse buckets ----
__global__ __launch_bounds__(256) void k_fill2(const int* __restrict__ ei,
                                               const float* __restrict__ attr,
                                               const float* __restrict__ W_e1,
                                               const float* __restrict__ b_e1,
                                               const float* __restrict__ W_e2,
                                               const float* __restrict__ b_e2,
                                               const int* __restrict__ bb,
                                               const int* __restrict__ H2,
                                               int2* __restrict__ rec,
                                               int E, int ce, int NB) {
    __shared__ int off[NBMAX];
    int c = blockIdx.x;
    for (int b = threadIdx.x; b < NB; b += 256)
        off[b] = bb[b] + H2[(size_t)c * NB + b];
    __syncthreads();
    float w1s = W_e1[0], w1d = W_e1[1], w1a = W_e1[2], bb1 = b_e1[0];
    float w2 = W_e2[0], bb2 = b_e2[0];
    int e0 = c * ce, e1 = min(e0 + ce, E);
    int nv = (e1 - e0) & ~3;
    const int4*   src4 = (const int4*)(ei + e0);
    const int4*   dst4 = (const int4*)(ei + E + e0);
    const float4* att4 = (const float4*)(attr + e0);
    for (int v = threadIdx.x; v < (nv >> 2); v += 256) {
        int4 sv = src4[v];
        int4 dv = dst4[v];
        float4 av = att4[v];
        int   ss[4] = {sv.x, sv.y, sv.z, sv.w};
        int   dd[4] = {dv.x, dv.y, dv.z, dv.w};
        float aa[4] = {av.x, av.y, av.z, av.w};
        #pragma unroll
        for (int k = 0; k < 4; k++) {
            float h = fmaxf((float)ss[k] * w1s + (float)dd[k] * w1d + aa[k] * w1a + bb1, 0.0f);
            float w = 1.0f / (1.0f + expf(-(h * w2 + bb2)));
            int pos = atomicAdd(&off[dd[k] >> BSH], 1);        // LDS atomic
            int2 rv;
            rv.x = ss[k] | ((dd[k] & (BS - 1)) << 16);
            rv.y = __float_as_int(w);
            rec[pos] = rv;
        }
    }
    for (int e = e0 + nv + threadIdx.x; e < e1; e += 256) {    // tail
        int d = ei[E + e];
        int s = ei[e];
        float h = fmaxf((float)s * w1s + (float)d * w1d + attr[e] * w1a + bb1, 0.0f);
        float w = 1.0f / (1.0f + expf(-(h * w2 + bb2)));
        int pos = atomicAdd(&off[d >> BSH], 1);
        int2 rv;
        rv.x = s | ((d & (BS - 1)) << 16);
        rv.y = __float_as_int(w);
        rec[pos] = rv;
    }
}

// ---- pass 5: per-bucket node sort + deg + dis + rowptr; emits packed 4 B rec3 ----
// rec3[j] = src | fp16(w) << 16   (dis folded into xws rows, not records)
__global__ __launch_bounds__(256) void k_bucket(const int2* __restrict__ rec,
                                                const int* __restrict__ bb,
                                                unsigned int* __restrict__ rec3,
                                                int* __restrict__ rowptr,
                                                float* __restrict__ dis, int n) {
    __shared__ int   cntL[BS];
    __shared__ float degL[BS];
    __shared__ int   pfx[BS];
    __shared__ int   cnt2[BS];
    int b = blockIdx.x;
    int t = threadIdx.x;
    if (t < BS) { cntL[t] = 0; degL[t] = 1.0f; cnt2[t] = 0; }   // self-loop deg=1
    __syncthreads();
    int s0 = bb[b], s1 = bb[b + 1];
    for (int j = s0 + t; j < s1; j += 256) {
        int2 rv = rec[j];
        int dl = (rv.x >> 16) & (BS - 1);
        atomicAdd(&cntL[dl], 1);
        atomicAdd(&degL[dl], __int_as_float(rv.y));    // fp32 LDS atomic (deg accuracy)
    }
    __syncthreads();
    if (t == 0) {
        int acc = 0;
        for (int k = 0; k < BS; k++) { pfx[k] = acc; acc += cntL[k]; }
    }
    __syncthreads();
    int lo = b << BSH;
    if (t < BS) {
        int i = lo + t;
        if (i < n) {
            rowptr[i] = s0 + pfx[t];
            dis[i] = rsqrtf(degL[t]);
        }
    }
    for (int j = s0 + t; j < s1; j += 256) {
        int2 rv = rec[j];
        int dl = (rv.x >> 16) & (BS - 1);
        int r = atomicAdd(&cnt2[dl], 1);
        unsigned int hh = (unsigned int)__half_as_ushort(
                              __float2half(__int_as_float(rv.y)));
        rec3[s0 + pfx[dl] + r] = (unsigned int)(rv.x & 0xFFFF) | (hh << 16);
    }
}

// ---- xws = dis .* (x @ W_gcn), stored fp16 row-major ----
__global__ __launch_bounds__(256) void k_xw(const float* __restrict__ x,
                                            const float* __restrict__ Wg,
                                            const float* __restrict__ dis,
                                            __half* __restrict__ xwh, int n) {
    __shared__ float xs[16 * 128];
    int block_row = blockIdx.x * 16;
    int tid = threadIdx.x;
    #pragma unroll
    for (int i = 0; i < 8; i++) {
        int idx = tid + i * 256;
        int r = idx >> 7, c = idx & 127;
        int gr = block_row + r;
        xs[idx] = (gr < n) ? x[(size_t)gr * 128 + c] : 0.0f;
    }
    __syncthreads();
    int c = tid & 127;
    int rbase = (tid >> 7) * 8;
    float acc[8] = {0, 0, 0, 0, 0, 0, 0, 0};
    for (int k = 0; k < 128; k += 4) {
        float4 xv[8];
        #pragma unroll
        for (int r = 0; r < 8; r++)
            xv[r] = *(const float4*)&xs[(rbase + r) * 128 + k];   // ds_read_b128 broadcast
        #pragma unroll
        for (int kk = 0; kk < 4; kk++) {
            float wv = Wg[(k + kk) * 128 + c];
            #pragma unroll
            for (int r = 0; r < 8; r++) {
                const float* xp = (const float*)&xv[r];
                acc[r] += xp[kk] * wv;
            }
        }
    }
    #pragma unroll
    for (int r = 0; r < 8; r++) {
        int gr = block_row + rbase + r;
        if (gr < n) xwh[(size_t)gr * 128 + c] = __float2half(acc[r] * dis[gr]);
    }
}

// ---- gather: wave per node; 4 groups x 16 lanes; group g takes edge 4j+g,
// lane q loads 16 B (8 fp16 feats) of the src xws row ----
__global__ __launch_bounds__(256) void k_gather(const unsigned int* __restrict__ rec3,
                                                const int* __restrict__ rowptr,
                                                const float* __restrict__ dis,
                                                const __half* __restrict__ xh,
                                                const float* __restrict__ bg,
                                                __half* __restrict__ conv, int n) {
    int wave = threadIdx.x >> 6;
    int lane = threadIdx.x & 63;
    int g = lane >> 4;          // edge group 0..3
    int q = lane & 15;          // lane in group; features q*8 .. q*8+7
    int i = blockIdx.x * 4 + wave;
    if (i >= n) return;                      // wave-uniform
    int st = rowptr[i];
    int m = rowptr[i + 1] - st;
    float di = dis[i];
    float acc[8];
    {
        uint4 sr = *(const uint4*)(xh + (size_t)i * 128 + q * 8);
        const __half2* hp = (const __half2*)&sr;
        float sc = (g == 0) ? 1.0f : 0.0f;   // self term xws[i], counted once
        #pragma unroll
        for (int k = 0; k < 4; k++) {
            float2 f = __half22float2(hp[k]);
            acc[2 * k]     = sc * f.x;
            acc[2 * k + 1] = sc * f.y;
        }
    }
    for (int base = 0; base < m; base += 64) {
        int kk = min(64, m - base);
        unsigned int rv = 0u;
        if (lane < kk) rv = rec3[st + base + lane];
        int jn = (kk + 3) >> 2;
        #pragma unroll 8
        for (int j = 0; j < jn; j++) {
            unsigned int rvj = (unsigned int)__builtin_amdgcn_ds_bpermute(
                                   ((j << 2) + g) << 2, (int)rv);
            int s = rvj & 0xFFFF;
            float cf = __half2float(__ushort_as_half((unsigned short)(rvj >> 16)));
            uint4 rw = *(const uint4*)(xh + (size_t)s * 128 + q * 8);
            const __half2* rp = (const __half2*)&rw;
            #pragma unroll
            for (int k = 0; k < 4; k++) {
                float2 f = __half22float2(rp[k]);
                acc[2 * k]     += cf * f.x;
                acc[2 * k + 1] += cf * f.y;
            }
        }
    }
    #pragma unroll
    for (int k = 0; k < 8; k++) {            // merge 4 group partials
        acc[k] += __shfl_xor(acc[k], 16);
        acc[k] += __shfl_xor(acc[k], 32);
    }
    if (g == 0) {                            // 16 lanes write the 256 B fp16 row
        float4 b0 = *(const float4*)(bg + q * 8);
        float4 b1 = *(const float4*)(bg + q * 8 + 4);
        const float* bp = (const float*)&b0;
        float v[8];
        #pragma unroll
        for (int k = 0; k < 4; k++) v[k] = fmaxf(di * acc[k] + bp[k], 0.0f);
        bp = (const float*)&b1;
        #pragma unroll
        for (int k = 0; k < 4; k++) v[4 + k] = fmaxf(di * acc[4 + k] + bp[k], 0.0f);
        __half2 h[4];
        #pragma unroll
        for (int k = 0; k < 4; k++)
            h[k] = __halves2half2(__float2half(v[2 * k]), __float2half(v[2 * k + 1]));
        uint4 o;
        o.x = *(unsigned int*)&h[0];
        o.y = *(unsigned int*)&h[1];
        o.z = *(unsigned int*)&h[2];
        o.w = *(unsigned int*)&h[3];
        *(uint4*)(conv + (size_t)i * 128 + q * 8) = o;
    }
}

// ---- mean-pool (h1 in fp16): batch sorted -> running accumulate ----
__global__ __launch_bounds__(128) void k_pool(const __half* __restrict__ h1,
                                              const int* __restrict__ batch,
                                              float* __restrict__ psum,
                                              float* __restrict__ pcnt, int n) {
    int f = threadIdx.x;
    int n0 = blockIdx.x * 64;
    if (n0 >= n) return;
    int n1 = min(n0 + 64, n);
    int cur = batch[n0];
    float acc = 0.0f, cnt = 0.0f;
    for (int i = n0; i < n1; i++) {
        int g = batch[i];
        if (g != cur) {
            atomicAdd(&psum[cur * 128 + f], acc);
            if (f == 0) atomicAdd(&pcnt[cur], cnt);
            acc = 0.0f; cnt = 0.0f; cur = g;
        }
        acc += __half2float(h1[(size_t)i * 128 + f]);
        cnt += 1.0f;
    }
    atomicAdd(&psum[cur * 128 + f], acc);
    if (f == 0) atomicAdd(&pcnt[cur], cnt);
}

// ---- head: pooled = psum/cnt; h2 = relu(pooled@W2+b2); out = h2@W3+b3 ----
__global__ __launch_bounds__(128) void k_head(const float* __restrict__ psum,
                                              const float* __restrict__ pcnt,
                                              const float* __restrict__ W2,
                                              const float* __restrict__ b2,
                                              const float* __restrict__ W3,
                                              const float* __restrict__ b3,
                                              float* __restrict__ out) {
    __shared__ float pl[128];
    __shared__ float h2s[128];
    int g = blockIdx.x;
    int t = threadIdx.x;
    float c = fmaxf(pcnt[g], 1.0f);
    pl[t] = psum[g * 128 + t] / c;
    __syncthreads();
    float acc = b2[t];
    for (int k = 0; k < 128; k++) acc += pl[k] * W2[k * 128 + t];
    h2s[t] = fmaxf(acc, 0.0f);
    __syncthreads();
    if (t < AD) {
        float o = b3[t];
        for (int k = 0; k < 128; k++) o += h2s[k] * W3[k * AD + t];
        out[g * AD + t] = o;
    }
}

extern "C" void kernel_launch(void* const* d_in, const int* in_sizes, int n_in,
                              void* d_out, int out_size, void* d_ws, size_t ws_size,
                              hipStream_t stream) {
    const float* x        = (const float*)d_in[0];
    const float* edge_attr= (const float*)d_in[1];
    const float* W_e1     = (const float*)d_in[2];
    const float* b_e1     = (const float*)d_in[3];
    const float* W_e2     = (const float*)d_in[4];
    const float* b_e2     = (const float*)d_in[5];
    const float* W_gcn    = (const float*)d_in[6];
    const float* b_gcn    = (const float*)d_in[7];
    const float* W2       = (const float*)d_in[8];
    const float* b2       = (const float*)d_in[9];
    const float* W3       = (const float*)d_in[10];
    const float* b3       = (const float*)d_in[11];
    const int*   ei       = (const int*)d_in[12];
    const int*   batch    = (const int*)d_in[13];
    float* out = (float*)d_out;

    const int E  = in_sizes[12] / 2;          // 1,600,000
    const int n  = in_sizes[13];              // 50,000 (<= 65536 for packing)
    const int NB = (n + BS - 1) >> BSH;       // 782 coarse buckets
    const int ce = (((E + NC2 - 1) / NC2) + 3) & ~3;   // edges per chunk, mult of 4

    // workspace layout (~45 MB)
    char* p = (char*)d_ws;
    __half* xwh   = (__half*)p;  p += (size_t)n * 128 * sizeof(__half);   // 12.8 MB
    int*    H2    = (int*)p;                                              // 3.2 MB, aliases conv
    __half* conv  = (__half*)p;  p += (size_t)n * 128 * sizeof(__half);   // 12.8 MB
    int2*   rec   = (int2*)p;    p += (size_t)E * sizeof(int2);           // 12.8 MB
    unsigned int* rec3 = (unsigned int*)p; p += (size_t)E * sizeof(unsigned int); // 6.4 MB
    float*  dis   = (float*)p;   p += (size_t)n * sizeof(float);
    float*  psum  = (float*)p;   p += (size_t)GB * 128 * sizeof(float);
    float*  pcnt  = (float*)p;   p += (size_t)GB * sizeof(float);         // contiguous after psum
    int*    rowptr= (int*)p;     p += (size_t)(n + 1) * sizeof(int);
    int*    cntB  = (int*)p;     p += (size_t)NBMAX * sizeof(int);
    int*    bb    = (int*)p;     p += (size_t)(NBMAX + 1) * sizeof(int);

    k_hist2<<<NC2, 256, 0, stream>>>(ei, H2, E, ce, NB);
    k_cscan<<<NB, 256, 0, stream>>>(H2, cntB, NB, NC2);
    k_bscan<<<1, 1024, 0, stream>>>(cntB, bb, rowptr, psum, NB, n, E);
    k_fill2<<<NC2, 256, 0, stream>>>(ei, edge_attr, W_e1, b_e1, W_e2, b_e2,
                                     bb, H2, rec, E, ce, NB);
    k_bucket<<<NB, 256, 0, stream>>>(rec, bb, rec3, rowptr, dis, n);
    k_xw<<<(n + 15) / 16, 256, 0, stream>>>(x, W_gcn, dis, xwh, n);
    k_gather<<<(n + 3) / 4, 256, 0, stream>>>(rec3, rowptr, dis, xwh,
                                              b_gcn, conv, n);
    k_pool<<<(n + 63) / 64, 128, 0, stream>>>(conv, batch, psum, pcnt, n);
    k_head<<<GB, 128, 0, stream>>>(psum, pcnt, W2, b2, W3, b3, out);
}

// Round 10
// 253.098 us; speedup vs baseline: 1.6110x; 1.1195x over previous
//
#include <hip/hip_runtime.h>
#include <hip/hip_fp16.h>
#include <math.h>

#define GB 64        // graphs in batch
#define AD 8         // n_actions
#define NC2 1024     // edge chunks for hist/fill
#define BSH 6        // bucket shift -> bucket covers 64 consecutive dst nodes
#define BS  64       // bucket size (nodes)
#define NBMAX 1024   // max coarse buckets (n <= 65536; src packing needs n <= 65536)

typedef _Float16 half8 __attribute__((ext_vector_type(8)));
typedef float    f32x4 __attribute__((ext_vector_type(4)));

// ---- pass 1: per-chunk LDS histogram of coarse bucket (dst>>6) ----
__global__ __launch_bounds__(256) void k_hist2(const int* __restrict__ ei,
                                               int* __restrict__ H2,
                                               int E, int ce, int NB) {
    __shared__ int h[NBMAX];
    int c = blockIdx.x;
    for (int b = threadIdx.x; b < NB; b += 256) h[b] = 0;
    __syncthreads();
    int e0 = c * ce, e1 = min(e0 + ce, E);
    int nv = (e1 - e0) & ~3;
    const int4* dst4 = (const int4*)(ei + E + e0);
    for (int v = threadIdx.x; v < (nv >> 2); v += 256) {
        int4 d = dst4[v];
        atomicAdd(&h[d.x >> BSH], 1);
        atomicAdd(&h[d.y >> BSH], 1);
        atomicAdd(&h[d.z >> BSH], 1);
        atomicAdd(&h[d.w >> BSH], 1);
    }
    for (int e = e0 + nv + threadIdx.x; e < e1; e += 256)   // tail
        atomicAdd(&h[ei[E + e] >> BSH], 1);
    __syncthreads();
    for (int b = threadIdx.x; b < NB; b += 256)
        H2[(size_t)c * NB + b] = h[b];                 // coalesced
}

// ---- pass 2: per-bucket exclusive prefix across chunks (one block per bucket) ----
__global__ __launch_bounds__(256) void k_cscan(int* __restrict__ H2,
                                               int* __restrict__ cntB,
                                               int NB, int nc) {
    __shared__ int ssum[256];
    int b = blockIdx.x;
    int t = threadIdx.x;
    int v[4];
    int local = 0;
    #pragma unroll
    for (int k = 0; k < 4; k++) {
        int c = t * 4 + k;                 // nc == 1024 == 256*4
        v[k] = (c < nc) ? H2[(size_t)c * NB + b] : 0;
        local += v[k];
    }
    ssum[t] = local;
    __syncthreads();
    for (int s = 1; s < 256; s <<= 1) {
        int tmp = (t >= s) ? ssum[t - s] : 0;
        __syncthreads();
        ssum[t] += tmp;
        __syncthreads();
    }
    int run = ssum[t] - local;
    #pragma unroll
    for (int k = 0; k < 4; k++) {
        int c = t * 4 + k;
        if (c < nc) H2[(size_t)c * NB + b] = run;
        run += v[k];
    }
    if (t == 255) cntB[b] = ssum[255];
}

// ---- pass 3: scan bucket totals -> bb[]; sentinels; zero psum/pcnt ----
__global__ __launch_bounds__(1024) void k_bscan(const int* __restrict__ cntB,
                                                int* __restrict__ bb,
                                                int* __restrict__ rowptr,
                                                float* __restrict__ psum,
                                                int NB, int n, int E) {
    __shared__ int sm[1024];
    int t = threadIdx.x;
    for (int z = t; z < GB * 128 + GB; z += 1024) psum[z] = 0.0f;  // psum+pcnt
    int v = (t < NB) ? cntB[t] : 0;
    sm[t] = v;
    __syncthreads();
    for (int s = 1; s < 1024; s <<= 1) {
        int tmp = (t >= s) ? sm[t - s] : 0;
        __syncthreads();
        sm[t] += tmp;
        __syncthreads();
    }
    if (t < NB) bb[t] = sm[t] - v;                     // exclusive
    if (t == NB - 1) bb[NB] = sm[t];                   // == E
    if (t == 0) rowptr[n] = E;                         // CSR sentinel
}

// ---- pass 4: edge MLP + scatter 8 B records into coarse buckets ----
__global__ __launch_bounds__(256) void k_fill2(const int* __restrict__ ei,
                                               const float* __restrict__ attr,
                                               const float* __restrict__ W_e1,
                                               const float* __restrict__ b_e1,
                                               const float* __restrict__ W_e2,
                                               const float* __restrict__ b_e2,
                                               const int* __restrict__ bb,
                                               const int* __restrict__ H2,
                                               int2* __restrict__ rec,
                                               int E, int ce, int NB) {
    __shared__ int off[NBMAX];
    int c = blockIdx.x;
    for (int b = threadIdx.x; b < NB; b += 256)
        off[b] = bb[b] + H2[(size_t)c * NB + b];
    __syncthreads();
    float w1s = W_e1[0], w1d = W_e1[1], w1a = W_e1[2], bb1 = b_e1[0];
    float w2 = W_e2[0], bb2 = b_e2[0];
    int e0 = c * ce, e1 = min(e0 + ce, E);
    int nv = (e1 - e0) & ~3;
    const int4*   src4 = (const int4*)(ei + e0);
    const int4*   dst4 = (const int4*)(ei + E + e0);
    const float4* att4 = (const float4*)(attr + e0);
    for (int v = threadIdx.x; v < (nv >> 2); v += 256) {
        int4 sv = src4[v];
        int4 dv = dst4[v];
        float4 av = att4[v];
        int   ss[4] = {sv.x, sv.y, sv.z, sv.w};
        int   dd[4] = {dv.x, dv.y, dv.z, dv.w};
        float aa[4] = {av.x, av.y, av.z, av.w};
        #pragma unroll
        for (int k = 0; k < 4; k++) {
            float h = fmaxf((float)ss[k] * w1s + (float)dd[k] * w1d + aa[k] * w1a + bb1, 0.0f);
            float w = 1.0f / (1.0f + expf(-(h * w2 + bb2)));
            int pos = atomicAdd(&off[dd[k] >> BSH], 1);        // LDS atomic
            int2 rv;
            rv.x = ss[k] | ((dd[k] & (BS - 1)) << 16);
            rv.y = __float_as_int(w);
            rec[pos] = rv;
        }
    }
    for (int e = e0 + nv + threadIdx.x; e < e1; e += 256) {    // tail
        int d = ei[E + e];
        int s = ei[e];
        float h = fmaxf((float)s * w1s + (float)d * w1d + attr[e] * w1a + bb1, 0.0f);
        float w = 1.0f / (1.0f + expf(-(h * w2 + bb2)));
        int pos = atomicAdd(&off[d >> BSH], 1);
        int2 rv;
        rv.x = s | ((d & (BS - 1)) << 16);
        rv.y = __float_as_int(w);
        rec[pos] = rv;
    }
}

// ---- pass 5: per-bucket node sort + deg + dis + rowptr; emits packed 4 B rec3 ----
__global__ __launch_bounds__(256) void k_bucket(const int2* __restrict__ rec,
                                                const int* __restrict__ bb,
                                                unsigned int* __restrict__ rec3,
                                                int* __restrict__ rowptr,
                                                float* __restrict__ dis, int n) {
    __shared__ int   cntL[BS];
    __shared__ float degL[BS];
    __shared__ int   pfx[BS];
    __shared__ int   cnt2[BS];
    int b = blockIdx.x;
    int t = threadIdx.x;
    if (t < BS) { cntL[t] = 0; degL[t] = 1.0f; cnt2[t] = 0; }   // self-loop deg=1
    __syncthreads();
    int s0 = bb[b], s1 = bb[b + 1];
    for (int j = s0 + t; j < s1; j += 256) {
        int2 rv = rec[j];
        int dl = (rv.x >> 16) & (BS - 1);
        atomicAdd(&cntL[dl], 1);
        atomicAdd(&degL[dl], __int_as_float(rv.y));    // fp32 LDS atomic (deg accuracy)
    }
    __syncthreads();
    if (t == 0) {
        int acc = 0;
        for (int k = 0; k < BS; k++) { pfx[k] = acc; acc += cntL[k]; }
    }
    __syncthreads();
    int lo = b << BSH;
    if (t < BS) {
        int i = lo + t;
        if (i < n) {
            rowptr[i] = s0 + pfx[t];
            dis[i] = rsqrtf(degL[t]);
        }
    }
    for (int j = s0 + t; j < s1; j += 256) {
        int2 rv = rec[j];
        int dl = (rv.x >> 16) & (BS - 1);
        int r = atomicAdd(&cnt2[dl], 1);
        unsigned int hh = (unsigned int)__half_as_ushort(
                              __float2half(__int_as_float(rv.y)));
        rec3[s0 + pfx[dl] + r] = (unsigned int)(rv.x & 0xFFFF) | (hh << 16);
    }
}

// ---- xws = dis .* (x @ W_gcn) via MFMA f16, fp32 accumulate ----
// block = 4 waves = 64 rows; wave w -> 16 rows; Wg staged in LDS transposed fp16.
// Layouts (HW-verified, cdna4 §3): A[m=lane&15][k=quad*8+j]; B[k=quad*8+j][n=lane&15];
// C/D: col=lane&15, row=quad*4+reg.
__global__ __launch_bounds__(256) void k_xw(const float* __restrict__ x,
                                            const float* __restrict__ Wg,
                                            const float* __restrict__ dis,
                                            __half* __restrict__ xwh, int n) {
    __shared__ _Float16 Wh[128 * 136];     // [n][k], +8 pad (272 B rows, 16B-aligned)
    int tid = threadIdx.x;
    for (int idx = tid; idx < 128 * 128; idx += 256) {
        int k = idx >> 7, c = idx & 127;   // Wg[k][c], coalesced read
        Wh[c * 136 + k] = (_Float16)Wg[idx];
    }
    __syncthreads();

    int lane = tid & 63;
    int w = tid >> 6;
    int n16 = lane & 15;
    int quad = lane >> 4;
    int r0 = blockIdx.x * 64 + w * 16;
    int arow = min(r0 + n16, n - 1);       // clamp (waves past n do dummy work)
    const float* xrow = x + (size_t)arow * 128;

    f32x4 acc[8];
    #pragma unroll
    for (int nt = 0; nt < 8; nt++) acc[nt] = (f32x4){0.f, 0.f, 0.f, 0.f};

    #pragma unroll
    for (int kk = 0; kk < 4; kk++) {
        int k0 = kk * 32 + quad * 8;
        float4 f0 = *(const float4*)(xrow + k0);
        float4 f1 = *(const float4*)(xrow + k0 + 4);
        half8 a;
        a[0] = (_Float16)f0.x; a[1] = (_Float16)f0.y;
        a[2] = (_Float16)f0.z; a[3] = (_Float16)f0.w;
        a[4] = (_Float16)f1.x; a[5] = (_Float16)f1.y;
        a[6] = (_Float16)f1.z; a[7] = (_Float16)f1.w;
        #pragma unroll
        for (int nt = 0; nt < 8; nt++) {
            half8 b = *(const half8*)&Wh[(nt * 16 + n16) * 136 + k0];
            acc[nt] = __builtin_amdgcn_mfma_f32_16x16x32_f16(a, b, acc[nt], 0, 0, 0);
        }
    }

    #pragma unroll
    for (int r = 0; r < 4; r++) {
        int row = r0 + quad * 4 + r;
        if (row < n) {
            float dv = dis[row];
            #pragma unroll
            for (int nt = 0; nt < 8; nt++)
                xwh[(size_t)row * 128 + nt * 16 + n16] = __float2half(acc[nt][r] * dv);
        }
    }
}

// ---- gather: wave per node; 4 groups x 16 lanes; group g takes edge 4j+g,
// lane q loads 16 B (8 fp16 feats) of the src xws row ----
__global__ __launch_bounds__(256) void k_gather(const unsigned int* __restrict__ rec3,
                                                const int* __restrict__ rowptr,
                                                const float* __restrict__ dis,
                                                const __half* __restrict__ xh,
                                                const float* __restrict__ bg,
                                                __half* __restrict__ conv, int n) {
    int wave = threadIdx.x >> 6;
    int lane = threadIdx.x & 63;
    int g = lane >> 4;          // edge group 0..3
    int q = lane & 15;          // lane in group; features q*8 .. q*8+7
    int i = blockIdx.x * 4 + wave;
    if (i >= n) return;                      // wave-uniform
    int st = rowptr[i];
    int m = rowptr[i + 1] - st;
    float di = dis[i];
    float acc[8];
    {
        uint4 sr = *(const uint4*)(xh + (size_t)i * 128 + q * 8);
        const __half2* hp = (const __half2*)&sr;
        float sc = (g == 0) ? 1.0f : 0.0f;   // self term xws[i], counted once
        #pragma unroll
        for (int k = 0; k < 4; k++) {
            float2 f = __half22float2(hp[k]);
            acc[2 * k]     = sc * f.x;
            acc[2 * k + 1] = sc * f.y;
        }
    }
    for (int base = 0; base < m; base += 64) {
        int kk = min(64, m - base);
        unsigned int rv = 0u;
        if (lane < kk) rv = rec3[st + base + lane];
        int jn = (kk + 3) >> 2;
        #pragma unroll 8
        for (int j = 0; j < jn; j++) {
            unsigned int rvj = (unsigned int)__builtin_amdgcn_ds_bpermute(
                                   ((j << 2) + g) << 2, (int)rv);
            int s = rvj & 0xFFFF;
            float cf = __half2float(__ushort_as_half((unsigned short)(rvj >> 16)));
            uint4 rw = *(const uint4*)(xh + (size_t)s * 128 + q * 8);
            const __half2* rp = (const __half2*)&rw;
            #pragma unroll
            for (int k = 0; k < 4; k++) {
                float2 f = __half22float2(rp[k]);
                acc[2 * k]     += cf * f.x;
                acc[2 * k + 1] += cf * f.y;
            }
        }
    }
    #pragma unroll
    for (int k = 0; k < 8; k++) {            // merge 4 group partials
        acc[k] += __shfl_xor(acc[k], 16);
        acc[k] += __shfl_xor(acc[k], 32);
    }
    if (g == 0) {                            // 16 lanes write the 256 B fp16 row
        float4 b0 = *(const float4*)(bg + q * 8);
        float4 b1 = *(const float4*)(bg + q * 8 + 4);
        const float* bp = (const float*)&b0;
        float v[8];
        #pragma unroll
        for (int k = 0; k < 4; k++) v[k] = fmaxf(di * acc[k] + bp[k], 0.0f);
        bp = (const float*)&b1;
        #pragma unroll
        for (int k = 0; k < 4; k++) v[4 + k] = fmaxf(di * acc[4 + k] + bp[k], 0.0f);
        __half2 h[4];
        #pragma unroll
        for (int k = 0; k < 4; k++)
            h[k] = __halves2half2(__float2half(v[2 * k]), __float2half(v[2 * k + 1]));
        uint4 o;
        o.x = *(unsigned int*)&h[0];
        o.y = *(unsigned int*)&h[1];
        o.z = *(unsigned int*)&h[2];
        o.w = *(unsigned int*)&h[3];
        *(uint4*)(conv + (size_t)i * 128 + q * 8) = o;
    }
}

// ---- mean-pool (h1 in fp16): batch sorted -> running accumulate ----
__global__ __launch_bounds__(128) void k_pool(const __half* __restrict__ h1,
                                              const int* __restrict__ batch,
                                              float* __restrict__ psum,
                                              float* __restrict__ pcnt, int n) {
    int f = threadIdx.x;
    int n0 = blockIdx.x * 64;
    if (n0 >= n) return;
    int n1 = min(n0 + 64, n);
    int cur = batch[n0];
    float acc = 0.0f, cnt = 0.0f;
    for (int i = n0; i < n1; i++) {
        int g = batch[i];
        if (g != cur) {
            atomicAdd(&psum[cur * 128 + f], acc);
            if (f == 0) atomicAdd(&pcnt[cur], cnt);
            acc = 0.0f; cnt = 0.0f; cur = g;
        }
        acc += __half2float(h1[(size_t)i * 128 + f]);
        cnt += 1.0f;
    }
    atomicAdd(&psum[cur * 128 + f], acc);
    if (f == 0) atomicAdd(&pcnt[cur], cnt);
}

// ---- head: pooled = psum/cnt; h2 = relu(pooled@W2+b2); out = h2@W3+b3 ----
__global__ __launch_bounds__(128) void k_head(const float* __restrict__ psum,
                                              const float* __restrict__ pcnt,
                                              const float* __restrict__ W2,
                                              const float* __restrict__ b2,
                                              const float* __restrict__ W3,
                                              const float* __restrict__ b3,
                                              float* __restrict__ out) {
    __shared__ float pl[128];
    __shared__ float h2s[128];
    int g = blockIdx.x;
    int t = threadIdx.x;
    float c = fmaxf(pcnt[g], 1.0f);
    pl[t] = psum[g * 128 + t] / c;
    __syncthreads();
    float acc = b2[t];
    for (int k = 0; k < 128; k++) acc += pl[k] * W2[k * 128 + t];
    h2s[t] = fmaxf(acc, 0.0f);
    __syncthreads();
    if (t < AD) {
        float o = b3[t];
        for (int k = 0; k < 128; k++) o += h2s[k] * W3[k * AD + t];
        out[g * AD + t] = o;
    }
}

extern "C" void kernel_launch(void* const* d_in, const int* in_sizes, int n_in,
                              void* d_out, int out_size, void* d_ws, size_t ws_size,
                              hipStream_t stream) {
    const float* x        = (const float*)d_in[0];
    const float* edge_attr= (const float*)d_in[1];
    const float* W_e1     = (const float*)d_in[2];
    const float* b_e1     = (const float*)d_in[3];
    const float* W_e2     = (const float*)d_in[4];
    const float* b_e2     = (const float*)d_in[5];
    const float* W_gcn    = (const float*)d_in[6];
    const float* b_gcn    = (const float*)d_in[7];
    const float* W2       = (const float*)d_in[8];
    const float* b2       = (const float*)d_in[9];
    const float* W3       = (const float*)d_in[10];
    const float* b3       = (const float*)d_in[11];
    const int*   ei       = (const int*)d_in[12];
    const int*   batch    = (const int*)d_in[13];
    float* out = (float*)d_out;

    const int E  = in_sizes[12] / 2;          // 1,600,000
    const int n  = in_sizes[13];              // 50,000 (<= 65536 for packing)
    const int NB = (n + BS - 1) >> BSH;       // 782 coarse buckets
    const int ce = (((E + NC2 - 1) / NC2) + 3) & ~3;   // edges per chunk, mult of 4

    // workspace layout (~45 MB)
    char* p = (char*)d_ws;
    __half* xwh   = (__half*)p;  p += (size_t)n * 128 * sizeof(__half);   // 12.8 MB
    int*    H2    = (int*)p;                                              // 3.2 MB, aliases conv
    __half* conv  = (__half*)p;  p += (size_t)n * 128 * sizeof(__half);   // 12.8 MB
    int2*   rec   = (int2*)p;    p += (size_t)E * sizeof(int2);           // 12.8 MB
    unsigned int* rec3 = (unsigned int*)p; p += (size_t)E * sizeof(unsigned int); // 6.4 MB
    float*  dis   = (float*)p;   p += (size_t)n * sizeof(float);
    float*  psum  = (float*)p;   p += (size_t)GB * 128 * sizeof(float);
    float*  pcnt  = (float*)p;   p += (size_t)GB * sizeof(float);         // contiguous after psum
    int*    rowptr= (int*)p;     p += (size_t)(n + 1) * sizeof(int);
    int*    cntB  = (int*)p;     p += (size_t)NBMAX * sizeof(int);
    int*    bb    = (int*)p;     p += (size_t)(NBMAX + 1) * sizeof(int);

    k_hist2<<<NC2, 256, 0, stream>>>(ei, H2, E, ce, NB);
    k_cscan<<<NB, 256, 0, stream>>>(H2, cntB, NB, NC2);
    k_bscan<<<1, 1024, 0, stream>>>(cntB, bb, rowptr, psum, NB, n, E);
    k_fill2<<<NC2, 256, 0, stream>>>(ei, edge_attr, W_e1, b_e1, W_e2, b_e2,
                                     bb, H2, rec, E, ce, NB);
    k_bucket<<<NB, 256, 0, stream>>>(rec, bb, rec3, rowptr, dis, n);
    k_xw<<<(n + 63) / 64, 256, 0, stream>>>(x, W_gcn, dis, xwh, n);
    k_gather<<<(n + 3) / 4, 256, 0, stream>>>(rec3, rowptr, dis, xwh,
                                              b_gcn, conv, n);
    k_pool<<<(n + 63) / 64, 128, 0, stream>>>(conv, batch, psum, pcnt, n);
    k_head<<<GB, 128, 0, stream>>>(psum, pcnt, W2, b2, W3, b3, out);
}

// Round 11
// 235.281 us; speedup vs baseline: 1.7330x; 1.0757x over previous
//
#include <hip/hip_runtime.h>
#include <hip/hip_fp16.h>
#include <math.h>

#define GB 64        // graphs in batch
#define AD 8         // n_actions
#define NC2 256      // edge chunks for hist/fill (fewer chunks -> line-sized record runs)
#define BSH 6        // bucket shift -> bucket covers 64 consecutive dst nodes
#define BS  64       // bucket size (nodes)
#define NBMAX 1024   // max coarse buckets (n <= 65536; src packing needs n <= 65536)

typedef _Float16 half8 __attribute__((ext_vector_type(8)));
typedef float    f32x4 __attribute__((ext_vector_type(4)));

// ---- pass 1: per-chunk LDS histogram of coarse bucket (dst>>6) ----
__global__ __launch_bounds__(512) void k_hist2(const int* __restrict__ ei,
                                               int* __restrict__ H2,
                                               int E, int ce, int NB) {
    __shared__ int h[NBMAX];
    int c = blockIdx.x;
    for (int b = threadIdx.x; b < NB; b += 512) h[b] = 0;
    __syncthreads();
    int e0 = c * ce, e1 = min(e0 + ce, E);
    int nv = (e1 - e0) & ~3;
    const int4* dst4 = (const int4*)(ei + E + e0);
    for (int v = threadIdx.x; v < (nv >> 2); v += 512) {
        int4 d = dst4[v];
        atomicAdd(&h[d.x >> BSH], 1);
        atomicAdd(&h[d.y >> BSH], 1);
        atomicAdd(&h[d.z >> BSH], 1);
        atomicAdd(&h[d.w >> BSH], 1);
    }
    for (int e = e0 + nv + threadIdx.x; e < e1; e += 512)   // tail
        atomicAdd(&h[ei[E + e] >> BSH], 1);
    __syncthreads();
    for (int b = threadIdx.x; b < NB; b += 512)
        H2[(size_t)c * NB + b] = h[b];                 // coalesced
}

// ---- pass 2: per-bucket exclusive prefix across chunks (one block per bucket) ----
__global__ __launch_bounds__(256) void k_cscan(int* __restrict__ H2,
                                               int* __restrict__ cntB,
                                               int NB, int nc) {
    __shared__ int ssum[256];
    int b = blockIdx.x;                    // bucket
    int t = threadIdx.x;
    int v = (t < nc) ? H2[(size_t)t * NB + b] : 0;   // nc == 256
    ssum[t] = v;
    __syncthreads();
    for (int s = 1; s < 256; s <<= 1) {
        int tmp = (t >= s) ? ssum[t - s] : 0;
        __syncthreads();
        ssum[t] += tmp;
        __syncthreads();
    }
    if (t < nc) H2[(size_t)t * NB + b] = ssum[t] - v;  // exclusive
    if (t == 255) cntB[b] = ssum[255];
}

// ---- pass 3: scan bucket totals -> bb[]; sentinels; zero psum/pcnt ----
__global__ __launch_bounds__(1024) void k_bscan(const int* __restrict__ cntB,
                                                int* __restrict__ bb,
                                                int* __restrict__ rowptr,
                                                float* __restrict__ psum,
                                                int NB, int n, int E) {
    __shared__ int sm[1024];
    int t = threadIdx.x;
    for (int z = t; z < GB * 128 + GB; z += 1024) psum[z] = 0.0f;  // psum+pcnt
    int v = (t < NB) ? cntB[t] : 0;
    sm[t] = v;
    __syncthreads();
    for (int s = 1; s < 1024; s <<= 1) {
        int tmp = (t >= s) ? sm[t - s] : 0;
        __syncthreads();
        sm[t] += tmp;
        __syncthreads();
    }
    if (t < NB) bb[t] = sm[t] - v;                     // exclusive
    if (t == NB - 1) bb[NB] = sm[t];                   // == E
    if (t == 0) rowptr[n] = E;                         // CSR sentinel
}

// ---- pass 4: edge MLP + scatter 8 B records into coarse buckets ----
__global__ __launch_bounds__(512) void k_fill2(const int* __restrict__ ei,
                                               const float* __restrict__ attr,
                                               const float* __restrict__ W_e1,
                                               const float* __restrict__ b_e1,
                                               const float* __restrict__ W_e2,
                                               const float* __restrict__ b_e2,
                                               const int* __restrict__ bb,
                                               const int* __restrict__ H2,
                                               int2* __restrict__ rec,
                                               int E, int ce, int NB) {
    __shared__ int off[NBMAX];
    int c = blockIdx.x;
    for (int b = threadIdx.x; b < NB; b += 512)
        off[b] = bb[b] + H2[(size_t)c * NB + b];
    __syncthreads();
    float w1s = W_e1[0], w1d = W_e1[1], w1a = W_e1[2], bb1 = b_e1[0];
    float w2 = W_e2[0], bb2 = b_e2[0];
    int e0 = c * ce, e1 = min(e0 + ce, E);
    int nv = (e1 - e0) & ~3;
    const int4*   src4 = (const int4*)(ei + e0);
    const int4*   dst4 = (const int4*)(ei + E + e0);
    const float4* att4 = (const float4*)(attr + e0);
    for (int v = threadIdx.x; v < (nv >> 2); v += 512) {
        int4 sv = src4[v];
        int4 dv = dst4[v];
        float4 av = att4[v];
        int   ss[4] = {sv.x, sv.y, sv.z, sv.w};
        int   dd[4] = {dv.x, dv.y, dv.z, dv.w};
        float aa[4] = {av.x, av.y, av.z, av.w};
        #pragma unroll
        for (int k = 0; k < 4; k++) {
            float h = fmaxf((float)ss[k] * w1s + (float)dd[k] * w1d + aa[k] * w1a + bb1, 0.0f);
            float w = 1.0f / (1.0f + expf(-(h * w2 + bb2)));
            int pos = atomicAdd(&off[dd[k] >> BSH], 1);        // LDS atomic
            int2 rv;
            rv.x = ss[k] | ((dd[k] & (BS - 1)) << 16);
            rv.y = __float_as_int(w);
            rec[pos] = rv;
        }
    }
    for (int e = e0 + nv + threadIdx.x; e < e1; e += 512) {    // tail
        int d = ei[E + e];
        int s = ei[e];
        float h = fmaxf((float)s * w1s + (float)d * w1d + attr[e] * w1a + bb1, 0.0f);
        float w = 1.0f / (1.0f + expf(-(h * w2 + bb2)));
        int pos = atomicAdd(&off[d >> BSH], 1);
        int2 rv;
        rv.x = s | ((d & (BS - 1)) << 16);
        rv.y = __float_as_int(w);
        rec[pos] = rv;
    }
}

// ---- pass 5: per-bucket node sort + deg + dis + rowptr; emits packed 4 B rec3 ----
__global__ __launch_bounds__(256) void k_bucket(const int2* __restrict__ rec,
                                                const int* __restrict__ bb,
                                                unsigned int* __restrict__ rec3,
                                                int* __restrict__ rowptr,
                                                float* __restrict__ dis, int n) {
    __shared__ int   cntL[BS];
    __shared__ float degL[BS];
    __shared__ int   pfx[BS];
    __shared__ int   cnt2[BS];
    int b = blockIdx.x;
    int t = threadIdx.x;
    if (t < BS) { cntL[t] = 0; degL[t] = 1.0f; cnt2[t] = 0; }   // self-loop deg=1
    __syncthreads();
    int s0 = bb[b], s1 = bb[b + 1];
    for (int j = s0 + t; j < s1; j += 256) {
        int2 rv = rec[j];
        int dl = (rv.x >> 16) & (BS - 1);
        atomicAdd(&cntL[dl], 1);
        atomicAdd(&degL[dl], __int_as_float(rv.y));    // fp32 LDS atomic (deg accuracy)
    }
    __syncthreads();
    if (t == 0) {
        int acc = 0;
        for (int k = 0; k < BS; k++) { pfx[k] = acc; acc += cntL[k]; }
    }
    __syncthreads();
    int lo = b << BSH;
    if (t < BS) {
        int i = lo + t;
        if (i < n) {
            rowptr[i] = s0 + pfx[t];
            dis[i] = rsqrtf(degL[t]);
        }
    }
    for (int j = s0 + t; j < s1; j += 256) {
        int2 rv = rec[j];
        int dl = (rv.x >> 16) & (BS - 1);
        int r = atomicAdd(&cnt2[dl], 1);
        unsigned int hh = (unsigned int)__half_as_ushort(
                              __float2half(__int_as_float(rv.y)));
        rec3[s0 + pfx[dl] + r] = (unsigned int)(rv.x & 0xFFFF) | (hh << 16);
    }
}

// ---- xws = dis .* (x @ W_gcn) via MFMA f16, fp32 accumulate ----
// block = 4 waves; 128 rows/block in two 64-row halves reusing staged Wh.
__global__ __launch_bounds__(256) void k_xw(const float* __restrict__ x,
                                            const float* __restrict__ Wg,
                                            const float* __restrict__ dis,
                                            __half* __restrict__ xwh, int n) {
    __shared__ _Float16 Wh[128 * 136];     // [n][k], +8 pad
    int tid = threadIdx.x;
    for (int idx = tid; idx < 128 * 128; idx += 256) {
        int k = idx >> 7, c = idx & 127;   // Wg[k][c], coalesced read
        Wh[c * 136 + k] = (_Float16)Wg[idx];
    }
    __syncthreads();

    int lane = tid & 63;
    int w = tid >> 6;
    int n16 = lane & 15;
    int quad = lane >> 4;

    #pragma unroll
    for (int hf = 0; hf < 2; hf++) {
        int r0 = blockIdx.x * 128 + hf * 64 + w * 16;
        if (r0 >= n) break;                    // wave-uniform (w uniform per wave)
        int arow = min(r0 + n16, n - 1);       // clamp
        const float* xrow = x + (size_t)arow * 128;

        f32x4 acc[8];
        #pragma unroll
        for (int nt = 0; nt < 8; nt++) acc[nt] = (f32x4){0.f, 0.f, 0.f, 0.f};

        #pragma unroll
        for (int kk = 0; kk < 4; kk++) {
            int k0 = kk * 32 + quad * 8;
            float4 f0 = *(const float4*)(xrow + k0);
            float4 f1 = *(const float4*)(xrow + k0 + 4);
            half8 a;
            a[0] = (_Float16)f0.x; a[1] = (_Float16)f0.y;
            a[2] = (_Float16)f0.z; a[3] = (_Float16)f0.w;
            a[4] = (_Float16)f1.x; a[5] = (_Float16)f1.y;
            a[6] = (_Float16)f1.z; a[7] = (_Float16)f1.w;
            #pragma unroll
            for (int nt = 0; nt < 8; nt++) {
                half8 b = *(const half8*)&Wh[(nt * 16 + n16) * 136 + k0];
                acc[nt] = __builtin_amdgcn_mfma_f32_16x16x32_f16(a, b, acc[nt], 0, 0, 0);
            }
        }

        #pragma unroll
        for (int r = 0; r < 4; r++) {
            int row = r0 + quad * 4 + r;
            if (row < n) {
                float dv = dis[row];
                #pragma unroll
                for (int nt = 0; nt < 8; nt++)
                    xwh[(size_t)row * 128 + nt * 16 + n16] = __float2half(acc[nt][r] * dv);
            }
        }
    }
}

// ---- gather: wave per node; 4 groups x 16 lanes; group g takes edge 4j+g,
// lane q loads 16 B (8 fp16 feats) of the src xws row ----
__global__ __launch_bounds__(256) void k_gather(const unsigned int* __restrict__ rec3,
                                                const int* __restrict__ rowptr,
                                                const float* __restrict__ dis,
                                                const __half* __restrict__ xh,
                                                const float* __restrict__ bg,
                                                __half* __restrict__ conv, int n) {
    int wave = threadIdx.x >> 6;
    int lane = threadIdx.x & 63;
    int g = lane >> 4;          // edge group 0..3
    int q = lane & 15;          // lane in group; features q*8 .. q*8+7
    int i = blockIdx.x * 4 + wave;
    if (i >= n) return;                      // wave-uniform
    int st = rowptr[i];
    int m = rowptr[i + 1] - st;
    float di = dis[i];
    float acc[8];
    {
        uint4 sr = *(const uint4*)(xh + (size_t)i * 128 + q * 8);
        const __half2* hp = (const __half2*)&sr;
        float sc = (g == 0) ? 1.0f : 0.0f;   // self term xws[i], counted once
        #pragma unroll
        for (int k = 0; k < 4; k++) {
            float2 f = __half22float2(hp[k]);
            acc[2 * k]     = sc * f.x;
            acc[2 * k + 1] = sc * f.y;
        }
    }
    for (int base = 0; base < m; base += 64) {
        int kk = min(64, m - base);
        unsigned int rv = 0u;
        if (lane < kk) rv = rec3[st + base + lane];
        int jn = (kk + 3) >> 2;
        #pragma unroll 8
        for (int j = 0; j < jn; j++) {
            unsigned int rvj = (unsigned int)__builtin_amdgcn_ds_bpermute(
                                   ((j << 2) + g) << 2, (int)rv);
            int s = rvj & 0xFFFF;
            float cf = __half2float(__ushort_as_half((unsigned short)(rvj >> 16)));
            uint4 rw = *(const uint4*)(xh + (size_t)s * 128 + q * 8);
            const __half2* rp = (const __half2*)&rw;
            #pragma unroll
            for (int k = 0; k < 4; k++) {
                float2 f = __half22float2(rp[k]);
                acc[2 * k]     += cf * f.x;
                acc[2 * k + 1] += cf * f.y;
            }
        }
    }
    #pragma unroll
    for (int k = 0; k < 8; k++) {            // merge 4 group partials
        acc[k] += __shfl_xor(acc[k], 16);
        acc[k] += __shfl_xor(acc[k], 32);
    }
    if (g == 0) {                            // 16 lanes write the 256 B fp16 row
        float4 b0 = *(const float4*)(bg + q * 8);
        float4 b1 = *(const float4*)(bg + q * 8 + 4);
        const float* bp = (const float*)&b0;
        float v[8];
        #pragma unroll
        for (int k = 0; k < 4; k++) v[k] = fmaxf(di * acc[k] + bp[k], 0.0f);
        bp = (const float*)&b1;
        #pragma unroll
        for (int k = 0; k < 4; k++) v[4 + k] = fmaxf(di * acc[4 + k] + bp[k], 0.0f);
        __half2 h[4];
        #pragma unroll
        for (int k = 0; k < 4; k++)
            h[k] = __halves2half2(__float2half(v[2 * k]), __float2half(v[2 * k + 1]));
        uint4 o;
        o.x = *(unsigned int*)&h[0];
        o.y = *(unsigned int*)&h[1];
        o.z = *(unsigned int*)&h[2];
        o.w = *(unsigned int*)&h[3];
        *(uint4*)(conv + (size_t)i * 128 + q * 8) = o;
    }
}

// ---- mean-pool: grid (graph, 4 chunks); binary-search bounds; half2 loads ----
__device__ __forceinline__ int lbound(const int* __restrict__ a, int n, int v) {
    int lo = 0, hi = n;
    while (lo < hi) {
        int mid = (lo + hi) >> 1;
        if (a[mid] < v) lo = mid + 1; else hi = mid;
    }
    return lo;
}

__global__ __launch_bounds__(256) void k_pool(const __half* __restrict__ h1,
                                              const int* __restrict__ batch,
                                              float* __restrict__ psum,
                                              float* __restrict__ pcnt, int n) {
    int g = blockIdx.x, ch = blockIdx.y;
    int t = threadIdx.x;
    int s = lbound(batch, n, g);
    int e = lbound(batch, n, g + 1);
    int rq = t >> 6, q = t & 63;
    float ax = 0.0f, ay = 0.0f;
    for (int i = s + ch * 4 + rq; i < e; i += 16) {
        __half2 hv = *(const __half2*)(h1 + (size_t)i * 128 + 2 * q);
        float2 f = __half22float2(hv);
        ax += f.x; ay += f.y;
    }
    __shared__ float2 sm[256];
    sm[t] = make_float2(ax, ay);
    __syncthreads();
    if (t < 64) {
        float2 a0 = sm[t], a1 = sm[t + 64], a2 = sm[t + 128], a3 = sm[t + 192];
        atomicAdd(&psum[g * 128 + 2 * q],     a0.x + a1.x + a2.x + a3.x);
        atomicAdd(&psum[g * 128 + 2 * q + 1], a0.y + a1.y + a2.y + a3.y);
    }
    if (ch == 0 && t == 0) pcnt[g] = (float)(e - s);
}

// ---- head: pooled = psum/cnt; h2 = relu(pooled@W2+b2); out = h2@W3+b3 ----
__global__ __launch_bounds__(128) void k_head(const float* __restrict__ psum,
                                              const float* __restrict__ pcnt,
                                              const float* __restrict__ W2,
                                              const float* __restrict__ b2,
                                              const float* __restrict__ W3,
                                              const float* __restrict__ b3,
                                              float* __restrict__ out) {
    __shared__ float pl[128];
    __shared__ float h2s[128];
    int g = blockIdx.x;
    int t = threadIdx.x;
    float c = fmaxf(pcnt[g], 1.0f);
    pl[t] = psum[g * 128 + t] / c;
    __syncthreads();
    float acc = b2[t];
    for (int k = 0; k < 128; k++) acc += pl[k] * W2[k * 128 + t];
    h2s[t] = fmaxf(acc, 0.0f);
    __syncthreads();
    if (t < AD) {
        float o = b3[t];
        for (int k = 0; k < 128; k++) o += h2s[k] * W3[k * AD + t];
        out[g * AD + t] = o;
    }
}

extern "C" void kernel_launch(void* const* d_in, const int* in_sizes, int n_in,
                              void* d_out, int out_size, void* d_ws, size_t ws_size,
                              hipStream_t stream) {
    const float* x        = (const float*)d_in[0];
    const float* edge_attr= (const float*)d_in[1];
    const float* W_e1     = (const float*)d_in[2];
    const float* b_e1     = (const float*)d_in[3];
    const float* W_e2     = (const float*)d_in[4];
    const float* b_e2     = (const float*)d_in[5];
    const float* W_gcn    = (const float*)d_in[6];
    const float* b_gcn    = (const float*)d_in[7];
    const float* W2       = (const float*)d_in[8];
    const float* b2       = (const float*)d_in[9];
    const float* W3       = (const float*)d_in[10];
    const float* b3       = (const float*)d_in[11];
    const int*   ei       = (const int*)d_in[12];
    const int*   batch    = (const int*)d_in[13];
    float* out = (float*)d_out;

    const int E  = in_sizes[12] / 2;          // 1,600,000
    const int n  = in_sizes[13];              // 50,000 (<= 65536 for packing)
    const int NB = (n + BS - 1) >> BSH;       // 782 coarse buckets
    const int ce = (((E + NC2 - 1) / NC2) + 3) & ~3;   // edges per chunk, mult of 4

    // workspace layout (~42 MB)
    char* p = (char*)d_ws;
    __half* xwh   = (__half*)p;  p += (size_t)n * 128 * sizeof(__half);   // 12.8 MB
    int*    H2    = (int*)p;                                              // 0.8 MB, aliases conv
    __half* conv  = (__half*)p;  p += (size_t)n * 128 * sizeof(__half);   // 12.8 MB
    int2*   rec   = (int2*)p;    p += (size_t)E * sizeof(int2);           // 12.8 MB
    unsigned int* rec3 = (unsigned int*)p; p += (size_t)E * sizeof(unsigned int); // 6.4 MB
    float*  dis   = (float*)p;   p += (size_t)n * sizeof(float);
    float*  psum  = (float*)p;   p += (size_t)GB * 128 * sizeof(float);
    float*  pcnt  = (float*)p;   p += (size_t)GB * sizeof(float);         // contiguous after psum
    int*    rowptr= (int*)p;     p += (size_t)(n + 1) * sizeof(int);
    int*    cntB  = (int*)p;     p += (size_t)NBMAX * sizeof(int);
    int*    bb    = (int*)p;     p += (size_t)(NBMAX + 1) * sizeof(int);

    k_hist2<<<NC2, 512, 0, stream>>>(ei, H2, E, ce, NB);
    k_cscan<<<NB, 256, 0, stream>>>(H2, cntB, NB, NC2);
    k_bscan<<<1, 1024, 0, stream>>>(cntB, bb, rowptr, psum, NB, n, E);
    k_fill2<<<NC2, 512, 0, stream>>>(ei, edge_attr, W_e1, b_e1, W_e2, b_e2,
                                     bb, H2, rec, E, ce, NB);
    k_bucket<<<NB, 256, 0, stream>>>(rec, bb, rec3, rowptr, dis, n);
    k_xw<<<(n + 127) / 128, 256, 0, stream>>>(x, W_gcn, dis, xwh, n);
    k_gather<<<(n + 3) / 4, 256, 0, stream>>>(rec3, rowptr, dis, xwh,
                                              b_gcn, conv, n);
    k_pool<<<dim3(GB, 4), 256, 0, stream>>>(conv, batch, psum, pcnt, n);
    k_head<<<GB, 128, 0, stream>>>(psum, pcnt, W2, b2, W3, b3, out);
}